// Round 1
// baseline (276.281 us; speedup 1.0000x reference)
//
#include <hip/hip_runtime.h>
#include <hip/hip_bf16.h>

#define NTOK   16384   // b*l = 4*4096
#define DIM    2048
#define NGRP   8
#define HDG    256
#define NIN    512     // K*HDG

typedef float f32x4 __attribute__((ext_vector_type(4)));
typedef short bf16x8 __attribute__((ext_vector_type(8)));

static __device__ __forceinline__ unsigned short f2bf(float f) {
    unsigned int u = __builtin_bit_cast(unsigned int, f);
    u = (u + 0x7fffu + ((u >> 16) & 1u)) >> 16;   // round-to-nearest-even
    return (unsigned short)u;
}

// ---------------- Kernel A: WmT[n][k] = bf16(Wm[k][n]) ----------------
__global__ __launch_bounds__(256) void prep_wm(const float* __restrict__ Wm,
                                               ushort* __restrict__ WmT) {
    __shared__ float tile[64][65];
    const int bk = blockIdx.x * 64;
    const int bn = blockIdx.y * 64;
    const int t = threadIdx.x;
    const int r = t >> 4;           // 0..15
    const int c = (t & 15) * 4;     // 0..60
#pragma unroll
    for (int i = 0; i < 4; i++) {
        const float4 v = *(const float4*)&Wm[(bk + r + i * 16) * 512 + bn + c];
        tile[r + i * 16][c + 0] = v.x;
        tile[r + i * 16][c + 1] = v.y;
        tile[r + i * 16][c + 2] = v.z;
        tile[r + i * 16][c + 3] = v.w;
    }
    __syncthreads();
#pragma unroll
    for (int i = 0; i < 4; i++) {
        const int n = r + i * 16;
        ushort4 o;
        o.x = f2bf(tile[c + 0][n]);
        o.y = f2bf(tile[c + 1][n]);
        o.z = f2bf(tile[c + 2][n]);
        o.w = f2bf(tile[c + 3][n]);
        *(ushort4*)&WmT[(bn + n) * 512 + bk + c] = o;
    }
}

// ------- Kernel B: gate (f32) + softmax + top2 + gather + out-copy -------
// block = 256 threads, 8 tokens per block. Thread t owns x elements t*8..t*8+7
// (all inside feature-group t>>5).
__global__ __launch_bounds__(256) void gate_gather(
        const float* __restrict__ x, const float* __restrict__ Wg,
        float* __restrict__ out, ushort* __restrict__ hbuf,
        int* __restrict__ Isel) {
    const int t = threadIdx.x;
    const int jg = t >> 5;          // which of the 8 groups this thread's slice lives in
    // Wg register-resident: wgr[j][g] = Wg[(t*8+j)*8 + g]
    float wgr[8][8];
#pragma unroll
    for (int j = 0; j < 8; j++) {
        const float4 a = *(const float4*)&Wg[(t * 8 + j) * 8];
        const float4 b = *(const float4*)&Wg[(t * 8 + j) * 8 + 4];
        wgr[j][0] = a.x; wgr[j][1] = a.y; wgr[j][2] = a.z; wgr[j][3] = a.w;
        wgr[j][4] = b.x; wgr[j][5] = b.y; wgr[j][6] = b.z; wgr[j][7] = b.w;
    }
    __shared__ float red[4][8];
    const int tok0 = blockIdx.x * 8;
    for (int tt = 0; tt < 8; tt++) {
        const int tok = tok0 + tt;
        const float4 x0 = *(const float4*)&x[tok * DIM + t * 8];
        const float4 x1 = *(const float4*)&x[tok * DIM + t * 8 + 4];
        const float xr[8] = {x0.x, x0.y, x0.z, x0.w, x1.x, x1.y, x1.z, x1.w};
        float acc[8];
#pragma unroll
        for (int g = 0; g < 8; g++) acc[g] = 0.f;
#pragma unroll
        for (int j = 0; j < 8; j++)
#pragma unroll
            for (int g = 0; g < 8; g++)
                acc[g] = fmaf(xr[j], wgr[j][g], acc[g]);
        // wave butterfly reduce (64 lanes)
#pragma unroll
        for (int g = 0; g < 8; g++) {
            float v = acc[g];
            v += __shfl_xor(v, 1, 64);
            v += __shfl_xor(v, 2, 64);
            v += __shfl_xor(v, 4, 64);
            v += __shfl_xor(v, 8, 64);
            v += __shfl_xor(v, 16, 64);
            v += __shfl_xor(v, 32, 64);
            acc[g] = v;
        }
        __syncthreads();   // protect red[] from previous iteration's readers
        if ((t & 63) == 0) {
#pragma unroll
            for (int g = 0; g < 8; g++) red[t >> 6][g] = acc[g];
        }
        __syncthreads();
        float lg[8];
#pragma unroll
        for (int g = 0; g < 8; g++)
            lg[g] = red[0][g] + red[1][g] + red[2][g] + red[3][g];
        // softmax + top2 (every thread redundantly; all static indexing)
        float m = lg[0];
#pragma unroll
        for (int g = 1; g < 8; g++) m = fmaxf(m, lg[g]);
        float sum = 0.f;
#pragma unroll
        for (int g = 0; g < 8; g++) sum += __expf(lg[g] - m);
        int i0 = 0; float b0 = lg[0];
#pragma unroll
        for (int g = 1; g < 8; g++) { if (lg[g] > b0) { b0 = lg[g]; i0 = g; } }
        int i1 = -1; float b1 = -3.4e38f;
#pragma unroll
        for (int g = 0; g < 8; g++) { if (g != i0 && lg[g] > b1) { b1 = lg[g]; i1 = g; } }
        const float inv = 1.0f / sum;
        const float G0 = __expf(b0 - m) * inv;
        const float G1 = __expf(b1 - m) * inv;

        if (jg == i0 || jg == i1) {
            const float gv  = (jg == i0) ? G0 : G1;
            const int  slot = (jg == i0) ? 0 : 1;
            int4 pk;
            pk.x = (int)f2bf(gv * xr[0]) | ((int)f2bf(gv * xr[1]) << 16);
            pk.y = (int)f2bf(gv * xr[2]) | ((int)f2bf(gv * xr[3]) << 16);
            pk.z = (int)f2bf(gv * xr[4]) | ((int)f2bf(gv * xr[5]) << 16);
            pk.w = (int)f2bf(gv * xr[6]) | ((int)f2bf(gv * xr[7]) << 16);
            *(int4*)&hbuf[tok * NIN + slot * HDG + (t & 31) * 8] = pk;
        } else {
            *(float4*)&out[tok * DIM + t * 8]     = x0;
            *(float4*)&out[tok * DIM + t * 8 + 4] = x1;
        }
        if (t == 0) { Isel[tok * 2] = i0; Isel[tok * 2 + 1] = i1; }
    }
}

// ------- Kernel C: h[16384,512](bf16) @ Wm[512,512] + bm, scatter into out -------
// 128x128 tile, 4 waves (2x2), each wave 64x64 = 4x4 frags of 16x16x32.
__global__ __launch_bounds__(256) void gemm_scatter(
        const ushort* __restrict__ h, const ushort* __restrict__ WmT,
        const float* __restrict__ bm, const int* __restrict__ Isel,
        float* __restrict__ out) {
    __shared__ ushort As[128][40];   // pad to 80B rows: 16B-aligned, ~2-way banks
    __shared__ ushort Bs[128][40];
    const int t = threadIdx.x;
    const int lane = t & 63;
    const int wave = t >> 6;
    const int wr = (wave >> 1) * 64;
    const int wc = (wave & 1) * 64;
    const int row0 = blockIdx.x * 128;
    const int n0 = blockIdx.y * 128;

    const int sr = t >> 2;           // staging row 0..63
    const int sc = (t & 3) * 8;      // staging col chunk (bf16 units)

    f32x4 acc[4][4];
#pragma unroll
    for (int i = 0; i < 4; i++)
#pragma unroll
        for (int j = 0; j < 4; j++)
            acc[i][j] = (f32x4){0.f, 0.f, 0.f, 0.f};

    for (int kk = 0; kk < 512; kk += 32) {
        __syncthreads();
        *(int4*)&As[sr][sc]      = *(const int4*)&h[(row0 + sr) * 512 + kk + sc];
        *(int4*)&As[sr + 64][sc] = *(const int4*)&h[(row0 + sr + 64) * 512 + kk + sc];
        *(int4*)&Bs[sr][sc]      = *(const int4*)&WmT[(n0 + sr) * 512 + kk + sc];
        *(int4*)&Bs[sr + 64][sc] = *(const int4*)&WmT[(n0 + sr + 64) * 512 + kk + sc];
        __syncthreads();
        const int fr = lane & 15;
        const int kh = (lane >> 4) * 8;
        bf16x8 av[4], bv[4];
#pragma unroll
        for (int i = 0; i < 4; i++) {
            av[i] = *(const bf16x8*)&As[wr + i * 16 + fr][kh];
            bv[i] = *(const bf16x8*)&Bs[wc + i * 16 + fr][kh];
        }
#pragma unroll
        for (int i = 0; i < 4; i++)
#pragma unroll
            for (int j = 0; j < 4; j++)
                acc[i][j] = __builtin_amdgcn_mfma_f32_16x16x32_bf16(
                    av[i], bv[j], acc[i][j], 0, 0, 0);
    }

    // epilogue: C row = token, col c in [0,512) -> out[token][Isel[token][c>>8]*256 + (c&255)]
    const int fr = lane & 15;
    const int rq = (lane >> 4) * 4;
    const int s    = (n0 + wc) >> 8;    // constant per wave per block
    const int ninh = (n0 + wc) & 255;
    float bmv[4];
#pragma unroll
    for (int j = 0; j < 4; j++) bmv[j] = bm[n0 + wc + j * 16 + fr];
#pragma unroll
    for (int i = 0; i < 4; i++) {
#pragma unroll
        for (int r = 0; r < 4; r++) {
            const int row = row0 + wr + i * 16 + rq + r;
            const int grp = Isel[row * 2 + s];
            float* op = &out[row * DIM + grp * HDG + ninh];
#pragma unroll
            for (int j = 0; j < 4; j++)
                op[j * 16 + fr] = acc[i][j][r] + bmv[j];
        }
    }
}

extern "C" void kernel_launch(void* const* d_in, const int* in_sizes, int n_in,
                              void* d_out, int out_size, void* d_ws, size_t ws_size,
                              hipStream_t stream) {
    const float* x  = (const float*)d_in[0];
    const float* Wg = (const float*)d_in[1];
    const float* Wm = (const float*)d_in[2];
    const float* bm = (const float*)d_in[3];
    float* out = (float*)d_out;

    char* ws = (char*)d_ws;
    ushort* hbuf = (ushort*)ws;                                   // 16 MiB
    ushort* WmT  = (ushort*)(ws + (size_t)16 * 1024 * 1024);      // 512 KiB
    int*    Isel = (int*)(ws + (size_t)16 * 1024 * 1024 + 512 * 1024);

    prep_wm<<<dim3(8, 8), 256, 0, stream>>>(Wm, WmT);
    gate_gather<<<NTOK / 8, 256, 0, stream>>>(x, Wg, out, hbuf, Isel);
    gemm_scatter<<<dim3(NTOK / 128, NIN / 128), 256, 0, stream>>>(hbuf, WmT, bm, Isel, out);
}